// Round 4
// baseline (193.767 us; speedup 1.0000x reference)
//
#include <hip/hip_runtime.h>

// HierarchicalEmbedding: e = s_new*lam + t_new*(1-lam)
//   s_new[i] = s[i] (i<nwp) else e_prime[cp[i]];  e_prime[j] = s[j]*lam[j] + t[j]*(1-lam[j])
//   t_new[i] = mean_{k<5} t[children_idx[5i+k]] (i<nwc) else t[i]
//
// Persistent-wave version: 2048 blocks, each 32-lane group strides over row-PAIRS.
// Per iteration: issue current pair's row gathers -> issue next pair's scalar/index
// loads (stay outstanding through compute: issued after the gathers in the in-order
// vmcnt queue) -> compute + store. 32 lanes/row, float4/lane (512B/row).

constexpr int E = 128;

__device__ __forceinline__ float4 ld4(const float* __restrict__ b, int r, int col) {
    return *reinterpret_cast<const float4*>(b + (size_t)r * E + col);
}

__global__ void __launch_bounds__(256)
he_kernel(const float* __restrict__ s,
          const float* __restrict__ t,
          const float* __restrict__ lambda_,
          const int* __restrict__ cp,
          const int* __restrict__ cidx,
          const int* __restrict__ nwc_p,
          const int* __restrict__ nwp_p,
          float* __restrict__ out,
          int n_rows)
{
    const int gid = blockIdx.x * blockDim.x + threadIdx.x;
    const int g   = gid >> 5;                    // 32-lane group id
    const int col = (gid & 31) << 2;             // float4 column
    const int G   = (gridDim.x * blockDim.x) >> 5;
    const int npairs = (n_rows + 1) >> 1;
    const int nwc = *nwc_p;
    const int nwp = *nwp_p;

    int p = g;
    if (p >= npairs) return;

    // ---- prefetched scalar state for current pair ----
    float lamA, lamB; int jA, jB;
    int a0, a1, a2, a3, a4, b0, b1, b2, b3, b4;
    bool chA, chB;
    {
        const int rA = 2 * p;
        const int rB = (2 * p + 1 < n_rows) ? 2 * p + 1 : n_rows - 1;
        lamA = lambda_[rA]; lamB = lambda_[rB];
        jA = (rA < nwp) ? rA : cp[rA];
        jB = (rB < nwp) ? rB : cp[rB];
        chA = rA < nwc; chB = rB < nwc;
        if (chA) { int q = rA * 5; a0 = cidx[q]; a1 = cidx[q+1]; a2 = cidx[q+2]; a3 = cidx[q+3]; a4 = cidx[q+4]; }
        else     { a0 = rA; a1 = a2 = a3 = a4 = rA; }
        if (chB) { int q = rB * 5; b0 = cidx[q]; b1 = cidx[q+1]; b2 = cidx[q+2]; b3 = cidx[q+3]; b4 = cidx[q+4]; }
        else     { b0 = rB; b1 = b2 = b3 = b4 = rB; }
    }

    while (true) {
        const int rA     = 2 * p;
        const int rB_raw = 2 * p + 1;
        const int rB     = (rB_raw < n_rows) ? rB_raw : n_rows - 1;
        const int pn     = p + G;
        const bool more  = pn < npairs;

        // ---- phase 1: issue ALL gathers for current pair (loads only) ----
        const float ljA_raw = lambda_[jA];
        const float ljB_raw = lambda_[jB];
        const float4 sjA = ld4(s, jA, col), tjA = ld4(t, jA, col);
        const float4 sjB = ld4(s, jB, col), tjB = ld4(t, jB, col);
        float4 u0, u1, u2, u3, u4, v0, v1, v2, v3, v4;
        if (chA) {
            u0 = ld4(t, a0, col); u1 = ld4(t, a1, col); u2 = ld4(t, a2, col);
            u3 = ld4(t, a3, col); u4 = ld4(t, a4, col);
        } else {
            u0 = ld4(t, a0, col);
        }
        if (chB) {
            v0 = ld4(t, b0, col); v1 = ld4(t, b1, col); v2 = ld4(t, b2, col);
            v3 = ld4(t, b3, col); v4 = ld4(t, b4, col);
        } else {
            v0 = ld4(t, b0, col);
        }

        // ---- phase 2: issue next pair's scalar/index loads (stay in flight) ----
        float nlamA = 0.f, nlamB = 0.f; int njA = 0, njB = 0;
        int na0 = 0, na1 = 0, na2 = 0, na3 = 0, na4 = 0;
        int nb0 = 0, nb1 = 0, nb2 = 0, nb3 = 0, nb4 = 0;
        bool nchA = false, nchB = false;
        if (more) {
            const int rA2 = 2 * pn;
            const int rB2 = (2 * pn + 1 < n_rows) ? 2 * pn + 1 : n_rows - 1;
            nlamA = lambda_[rA2]; nlamB = lambda_[rB2];
            njA = (rA2 < nwp) ? rA2 : cp[rA2];
            njB = (rB2 < nwp) ? rB2 : cp[rB2];
            nchA = rA2 < nwc; nchB = rB2 < nwc;
            if (nchA) { int q = rA2 * 5; na0 = cidx[q]; na1 = cidx[q+1]; na2 = cidx[q+2]; na3 = cidx[q+3]; na4 = cidx[q+4]; }
            else      { na0 = rA2; na1 = na2 = na3 = na4 = rA2; }
            if (nchB) { int q = rB2 * 5; nb0 = cidx[q]; nb1 = cidx[q+1]; nb2 = cidx[q+2]; nb3 = cidx[q+3]; nb4 = cidx[q+4]; }
            else      { nb0 = rB2; nb1 = nb2 = nb3 = nb4 = rB2; }
        }

        // ---- phase 3: consume, compute, store ----
        const float ljA = (rA < nwp) ? 1.0f : ljA_raw;
        const float ljB = (rB < nwp) ? 1.0f : ljB_raw;

        float4 tvA, tvB;
        if (chA) {
            tvA.x = (u0.x + u1.x + u2.x + u3.x + u4.x) * 0.2f;
            tvA.y = (u0.y + u1.y + u2.y + u3.y + u4.y) * 0.2f;
            tvA.z = (u0.z + u1.z + u2.z + u3.z + u4.z) * 0.2f;
            tvA.w = (u0.w + u1.w + u2.w + u3.w + u4.w) * 0.2f;
        } else {
            tvA = u0;
        }
        if (chB) {
            tvB.x = (v0.x + v1.x + v2.x + v3.x + v4.x) * 0.2f;
            tvB.y = (v0.y + v1.y + v2.y + v3.y + v4.y) * 0.2f;
            tvB.z = (v0.z + v1.z + v2.z + v3.z + v4.z) * 0.2f;
            tvB.w = (v0.w + v1.w + v2.w + v3.w + v4.w) * 0.2f;
        } else {
            tvB = v0;
        }

        float4 eA, eB;
        eA.x = (sjA.x * ljA + tjA.x * (1.0f - ljA)) * lamA + tvA.x * (1.0f - lamA);
        eA.y = (sjA.y * ljA + tjA.y * (1.0f - ljA)) * lamA + tvA.y * (1.0f - lamA);
        eA.z = (sjA.z * ljA + tjA.z * (1.0f - ljA)) * lamA + tvA.z * (1.0f - lamA);
        eA.w = (sjA.w * ljA + tjA.w * (1.0f - ljA)) * lamA + tvA.w * (1.0f - lamA);
        eB.x = (sjB.x * ljB + tjB.x * (1.0f - ljB)) * lamB + tvB.x * (1.0f - lamB);
        eB.y = (sjB.y * ljB + tjB.y * (1.0f - ljB)) * lamB + tvB.y * (1.0f - lamB);
        eB.z = (sjB.z * ljB + tjB.z * (1.0f - ljB)) * lamB + tvB.z * (1.0f - lamB);
        eB.w = (sjB.w * ljB + tjB.w * (1.0f - ljB)) * lamB + tvB.w * (1.0f - lamB);

        *reinterpret_cast<float4*>(out + (size_t)rA * E + col) = eA;
        if (rB_raw < n_rows)
            *reinterpret_cast<float4*>(out + (size_t)rB * E + col) = eB;

        if (!more) break;
        p = pn;
        lamA = nlamA; lamB = nlamB; jA = njA; jB = njB;
        chA = nchA; chB = nchB;
        a0 = na0; a1 = na1; a2 = na2; a3 = na3; a4 = na4;
        b0 = nb0; b1 = nb1; b2 = nb2; b3 = nb3; b4 = nb4;
    }
}

extern "C" void kernel_launch(void* const* d_in, const int* in_sizes, int n_in,
                              void* d_out, int out_size, void* d_ws, size_t ws_size,
                              hipStream_t stream)
{
    const float* s            = (const float*)d_in[0];
    const float* t            = (const float*)d_in[1];
    const float* lambda_      = (const float*)d_in[2];
    const int*   cp           = (const int*)d_in[3];
    const int*   children_idx = (const int*)d_in[4];
    // d_in[5] = seg_ids (implicit repeat(arange(nwc),5), unused)
    const int*   nwc_p        = (const int*)d_in[6];
    const int*   nwp_p        = (const int*)d_in[7];

    float* out = (float*)d_out;
    const int n_rows = in_sizes[0] / E;          // NODE_NUM+1

    const int threads = 256;
    const int blocks  = 2048;                    // persistent: 8192 waves = 32/CU

    he_kernel<<<blocks, threads, 0, stream>>>(s, t, lambda_, cp, children_idx,
                                              nwc_p, nwp_p, out, n_rows);
}

// Round 6
// 181.032 us; speedup vs baseline: 1.0703x; 1.0703x over previous
//
#include <hip/hip_runtime.h>

// HierarchicalEmbedding: e = s_new*lam + t_new*(1-lam)
//   s_new[i] = s[i] (i<nwp) else e_prime[cp[i]];  e_prime[j] = s[j]*lam[j] + t[j]*(1-lam[j])
//   t_new[i] = mean_{k<5} t[children_idx[5i+k]] (i<nwc) else t[i]
//
// Round-2 structure (32 lanes/row, float4/lane = 512B/row, one-shot waves) plus:
//  * REVERSED row order: blocks dispatch roughly in id order, so mapping
//    row = n_rows-1-row_id runs the upper rows (sequential t reads) FIRST,
//    warming the 256MB L3 with t before the child rows' random 5-way t
//    gathers run (t is exactly L3-sized).
//  * Non-temporal stores for out: 250MB of never-re-read write data stays
//    out of L2/L3, preserving t residency. (NT builtin needs a native Clang
//    vector type, not HIP's float4 class -> fv4.)

constexpr int E = 128;
typedef float fv4 __attribute__((ext_vector_type(4)));

__global__ void __launch_bounds__(256)
he_kernel(const float* __restrict__ s,
          const float* __restrict__ t,
          const float* __restrict__ lambda_,
          const int* __restrict__ cp,
          const int* __restrict__ children_idx,
          const int* __restrict__ nwc_p,
          const int* __restrict__ nwp_p,
          float* __restrict__ out,
          int n_rows)
{
    const int gid    = blockIdx.x * blockDim.x + threadIdx.x;
    const int row_id = gid >> 5;             // 32 threads per row
    const int col    = (gid & 31) << 2;      // float4 column offset
    if (row_id >= n_rows) return;
    const int row = n_rows - 1 - row_id;     // reversed: upper rows first

    const int nwc = *nwc_p;
    const int nwp = *nwp_p;

    const float lam = lambda_[row];

    // ---- s_new[row] ----
    float4 sv;
    if (row < nwp) {
        sv = *reinterpret_cast<const float4*>(s + (size_t)row * E + col);
    } else {
        const int   j  = cp[row];
        const float lj = lambda_[j];
        const float4 sj = *reinterpret_cast<const float4*>(s + (size_t)j * E + col);
        const float4 tj = *reinterpret_cast<const float4*>(t + (size_t)j * E + col);
        sv.x = sj.x * lj + tj.x * (1.0f - lj);
        sv.y = sj.y * lj + tj.y * (1.0f - lj);
        sv.z = sj.z * lj + tj.z * (1.0f - lj);
        sv.w = sj.w * lj + tj.w * (1.0f - lj);
    }

    // ---- t_new[row] ----
    float4 tv;
    if (row < nwc) {
        const int base = row * 5;
        int c0 = children_idx[base + 0];
        int c1 = children_idx[base + 1];
        int c2 = children_idx[base + 2];
        int c3 = children_idx[base + 3];
        int c4 = children_idx[base + 4];
        const float4 t0 = *reinterpret_cast<const float4*>(t + (size_t)c0 * E + col);
        const float4 t1 = *reinterpret_cast<const float4*>(t + (size_t)c1 * E + col);
        const float4 t2 = *reinterpret_cast<const float4*>(t + (size_t)c2 * E + col);
        const float4 t3 = *reinterpret_cast<const float4*>(t + (size_t)c3 * E + col);
        const float4 t4 = *reinterpret_cast<const float4*>(t + (size_t)c4 * E + col);
        tv.x = (t0.x + t1.x + t2.x + t3.x + t4.x) * 0.2f;
        tv.y = (t0.y + t1.y + t2.y + t3.y + t4.y) * 0.2f;
        tv.z = (t0.z + t1.z + t2.z + t3.z + t4.z) * 0.2f;
        tv.w = (t0.w + t1.w + t2.w + t3.w + t4.w) * 0.2f;
    } else {
        tv = *reinterpret_cast<const float4*>(t + (size_t)row * E + col);
    }

    // ---- e[row] ----
    fv4 ev;
    ev.x = sv.x * lam + tv.x * (1.0f - lam);
    ev.y = sv.y * lam + tv.y * (1.0f - lam);
    ev.z = sv.z * lam + tv.z * (1.0f - lam);
    ev.w = sv.w * lam + tv.w * (1.0f - lam);
    __builtin_nontemporal_store(ev, reinterpret_cast<fv4*>(out + (size_t)row * E + col));
}

extern "C" void kernel_launch(void* const* d_in, const int* in_sizes, int n_in,
                              void* d_out, int out_size, void* d_ws, size_t ws_size,
                              hipStream_t stream)
{
    const float* s            = (const float*)d_in[0];
    const float* t            = (const float*)d_in[1];
    const float* lambda_      = (const float*)d_in[2];
    const int*   cp           = (const int*)d_in[3];
    const int*   children_idx = (const int*)d_in[4];
    // d_in[5] = seg_ids (implicit repeat(arange(nwc),5), unused)
    const int*   nwc_p        = (const int*)d_in[6];
    const int*   nwp_p        = (const int*)d_in[7];

    float* out = (float*)d_out;
    const int n_rows = in_sizes[0] / E;   // NODE_NUM+1

    const int threads = 256;              // 8 rows per block (32 threads/row)
    const int rows_per_block = threads / 32;
    const int blocks = (n_rows + rows_per_block - 1) / rows_per_block;

    he_kernel<<<blocks, threads, 0, stream>>>(s, t, lambda_, cp, children_idx,
                                              nwc_p, nwp_p, out, n_rows);
}